// Round 3
// baseline (115.526 us; speedup 1.0000x reference)
//
#include <hip/hip_runtime.h>
#include <hip/hip_bf16.h>
#include <math.h>

#define Bq  2
#define Sq  512
#define Hq  768
#define NHq 12
#define HDq 64
#define SHsz (Bq * Sq * Hq)   // 786432 elems
#define WSZ  (Hq * Hq)        // 589824 elems

typedef __bf16 bf16x8 __attribute__((ext_vector_type(8)));
typedef unsigned short u16x8 __attribute__((ext_vector_type(8)));
typedef float f32x4 __attribute__((ext_vector_type(4)));

static __device__ __forceinline__ unsigned short f2bf(float f) {
    unsigned int u = __float_as_uint(f);
    u += 0x7fffu + ((u >> 16) & 1u);
    return (unsigned short)(u >> 16);
}

static __device__ __forceinline__ f32x4 mfma_bf16(bf16x8 a, bf16x8 b, f32x4 c) {
    return __builtin_amdgcn_mfma_f32_16x16x32_bf16(a, b, c, 0, 0, 0);
}

static __device__ __forceinline__ void async16(const void* g, void* l) {
    __builtin_amdgcn_global_load_lds(
        (const __attribute__((address_space(1))) void*)(uintptr_t)g,
        (__attribute__((address_space(3))) void*)(unsigned int)(uintptr_t)l,
        16, 0, 0);
}

// ---------------- fp32 -> bf16 pre-convert (inputs + 4 weights) ----------------
__global__ __launch_bounds__(256) void cvt_kernel(
    const float* __restrict__ from_h, const float* __restrict__ to_h,
    const float* __restrict__ Wq, const float* __restrict__ Wk,
    const float* __restrict__ Wvf, const float* __restrict__ Wvt,
    unsigned short* __restrict__ ws)
{
    const int z = blockIdx.y;
    const float* src; unsigned short* dst; int n;
    switch (z) {
        case 0:  src = from_h; dst = ws + 3 * SHsz;           n = SHsz; break;
        case 1:  src = to_h;   dst = ws + 4 * SHsz;           n = SHsz; break;
        case 2:  src = Wq;     dst = ws + 5 * SHsz;           n = WSZ;  break;
        case 3:  src = Wk;     dst = ws + 5 * SHsz + WSZ;     n = WSZ;  break;
        case 4:  src = Wvf;    dst = ws + 5 * SHsz + 2 * WSZ; n = WSZ;  break;
        default: src = Wvt;    dst = ws + 5 * SHsz + 3 * WSZ; n = WSZ;  break;
    }
    const int idx = (blockIdx.x * 256 + threadIdx.x) * 8;
    if (idx < n) {
        const float4 a = *(const float4*)(src + idx);
        const float4 b = *(const float4*)(src + idx + 4);
        u16x8 o = { f2bf(a.x), f2bf(a.y), f2bf(a.z), f2bf(a.w),
                    f2bf(b.x), f2bf(b.y), f2bf(b.z), f2bf(b.w) };
        *(u16x8*)(dst + idx) = o;
    }
}

// ---------------- projections: C = A @ W^T + b, 128x64 tile, BK=64 ----------------
// z=0: Q -> qbf [B*S,H]; z=1: K -> kbf; z=2: VT -> vtt [(b*NH+h)*HD+d, S]; z=3: VF -> outp fp32
__global__ __launch_bounds__(256) void proj_gemm(
    const unsigned short* __restrict__ fbf, const unsigned short* __restrict__ tbf,
    const unsigned short* __restrict__ wqb, const unsigned short* __restrict__ wkb,
    const unsigned short* __restrict__ wvfb, const unsigned short* __restrict__ wvtb,
    const float* __restrict__ bq, const float* __restrict__ bk,
    const float* __restrict__ bvf, const float* __restrict__ bvt,
    unsigned short* __restrict__ qbf, unsigned short* __restrict__ kbf,
    unsigned short* __restrict__ vtt, float* __restrict__ outp)
{
    __shared__ unsigned short lds[12288];  // A 128x64 [0,8192) + W 64x64 [8192,12288); reused for repack
    unsigned short* Als = lds;
    unsigned short* Wls = lds + 8192;

    const int z = blockIdx.z;
    const unsigned short *A, *W;
    const float* bias;
    if (z == 0)      { A = fbf; W = wqb;  bias = bq;  }
    else if (z == 1) { A = tbf; W = wkb;  bias = bk;  }
    else if (z == 2) { A = tbf; W = wvtb; bias = bvt; }
    else             { A = fbf; W = wvfb; bias = bvf; }

    const int t    = threadIdx.x;
    const int wv   = t >> 6;
    const int lane = t & 63;
    const int l16  = lane & 15;
    const int quad = lane >> 4;
    const int bn = blockIdx.x;   // 0..11 (one head each)
    const int bm = blockIdx.y;   // 0..7

    const int srow = lane >> 3;                 // 0..7
    const int sgrp = (lane & 7) ^ (srow & 7);   // swizzled global k-group

    f32x4 acc[2][4] = {};

    for (int kt = 0; kt < Hq / 64; ++kt) {
        __syncthreads();
        #pragma unroll
        for (int c = 0; c < 4; ++c) {   // A: 128 rows, wave wv handles rows wv*32 + c*8
            const int r0 = wv * 32 + c * 8;
            async16(A + (size_t)(bm * 128 + r0 + srow) * Hq + kt * 64 + sgrp * 8, &Als[r0 * 64]);
        }
        #pragma unroll
        for (int c = 0; c < 2; ++c) {   // W: 64 rows
            const int r0 = wv * 16 + c * 8;
            async16(W + (size_t)(bn * 64 + r0 + srow) * Hq + kt * 64 + sgrp * 8, &Wls[r0 * 64]);
        }
        __syncthreads();

        #pragma unroll
        for (int kk = 0; kk < 2; ++kk) {
            const int sg = ((kk * 4 + quad) ^ (l16 & 7)) * 8;
            bf16x8 af[2];
            #pragma unroll
            for (int i = 0; i < 2; ++i)
                af[i] = *(const bf16x8*)&Als[(wv * 32 + i * 16 + l16) * 64 + sg];
            #pragma unroll
            for (int j = 0; j < 4; ++j) {
                const bf16x8 bfr = *(const bf16x8*)&Wls[(j * 16 + l16) * 64 + sg];
                #pragma unroll
                for (int i = 0; i < 2; ++i)
                    acc[i][j] = mfma_bf16(af[i], bfr, acc[i][j]);
            }
        }
    }

    __syncthreads();   // LDS free for repack

    if (z == 3) {
        #pragma unroll
        for (int j = 0; j < 4; ++j) {
            const int ncol = bn * 64 + j * 16 + l16;
            const float bv = bias[ncol];
            #pragma unroll
            for (int i = 0; i < 2; ++i)
                #pragma unroll
                for (int r = 0; r < 4; ++r) {
                    const int m = bm * 128 + wv * 32 + i * 16 + quad * 4 + r;
                    outp[(size_t)m * Hq + ncol] = acc[i][j][r] + bv;
                }
        }
        return;
    }

    unsigned short* rep = lds;
    if (z == 2) {
        // rep[n_local 0..63][m_local 0..127], stride 136 shorts (272B, 16B-aligned)
        #pragma unroll
        for (int j = 0; j < 4; ++j) {
            const float bv = bias[bn * 64 + j * 16 + l16];
            #pragma unroll
            for (int i = 0; i < 2; ++i)
                #pragma unroll
                for (int r = 0; r < 4; ++r)
                    rep[(j * 16 + l16) * 136 + wv * 32 + i * 16 + quad * 4 + r] = f2bf(acc[i][j][r] + bv);
        }
        __syncthreads();
        const int row = t >> 2;          // d 0..63
        const int bb = bm >> 2, m0 = (bm & 3) * 128;
        #pragma unroll
        for (int p = 0; p < 4; ++p) {
            const int g = (t & 3) + p * 4;   // 0..15 m-groups
            const u16x8 v = *(const u16x8*)&rep[row * 136 + g * 8];
            *(u16x8*)&vtt[((size_t)((bb * NHq + bn) * HDq + row)) * Sq + m0 + g * 8] = v;
        }
    } else {
        // rep[m_local 0..127][n_local 0..63], stride 72 shorts (144B, 16B-aligned)
        #pragma unroll
        for (int j = 0; j < 4; ++j) {
            const float bv = bias[bn * 64 + j * 16 + l16];
            #pragma unroll
            for (int i = 0; i < 2; ++i)
                #pragma unroll
                for (int r = 0; r < 4; ++r)
                    rep[(wv * 32 + i * 16 + quad * 4 + r) * 72 + j * 16 + l16] = f2bf(acc[i][j][r] + bv);
        }
        __syncthreads();
        unsigned short* dstp = (z == 0) ? qbf : kbf;
        const int row = t >> 1;          // 0..127
        #pragma unroll
        for (int p = 0; p < 4; ++p) {
            const int g = (t & 1) * 4 + p;   // 0..7 n-groups
            const u16x8 v = *(const u16x8*)&rep[row * 72 + g * 8];
            *(u16x8*)&dstp[(size_t)(bm * 128 + row) * Hq + bn * 64 + g * 8] = v;
        }
    }
}

// ---------------- attention: out += softmax(QK^T/8 + mask) @ VT ----------------
// 1 wave / 16 q-rows, grid (32,12,2). K-tile = 64, fully unrolled, prefetched.
__global__ __launch_bounds__(64) void attn_kernel(
    const unsigned short* __restrict__ qbf,
    const unsigned short* __restrict__ kbf,
    const unsigned short* __restrict__ vtt,
    const float* __restrict__ amask,
    float* __restrict__ outp)
{
    __shared__ unsigned short Plds[16 * 72];

    const int t    = threadIdx.x;
    const int l16  = t & 15;
    const int quad = t >> 4;
    const int q0 = blockIdx.x * 16;
    const int h  = blockIdx.y;
    const int b  = blockIdx.z;

    const unsigned short* qrow = qbf + ((size_t)(b * Sq + q0 + l16)) * Hq + h * HDq + quad * 8;
    const bf16x8 aq0 = *(const bf16x8*)qrow;
    const bf16x8 aq1 = *(const bf16x8*)(qrow + 32);

    const unsigned short* kbase = kbf + ((size_t)(b * Sq + l16)) * Hq + h * HDq + quad * 8;
    const unsigned short* vbase = vtt + ((size_t)((b * NHq + h) * HDq + l16)) * Sq + quad * 8;

    f32x4 O[4] = {};
    float ts[4] = {0.f, 0.f, 0.f, 0.f};
    const float scale = 0.125f;

    bf16x8 kb[2][4][2];
    #pragma unroll
    for (int kg = 0; kg < 4; ++kg) {
        kb[0][kg][0] = *(const bf16x8*)(kbase + (size_t)(kg * 16) * Hq);
        kb[0][kg][1] = *(const bf16x8*)(kbase + (size_t)(kg * 16) * Hq + 32);
    }

    #pragma unroll
    for (int kt = 0; kt < Sq / 64; ++kt) {
        const int cur = kt & 1, nxt = cur ^ 1;
        const int k0 = kt * 64;

        f32x4 s[4] = {};
        #pragma unroll
        for (int kg = 0; kg < 4; ++kg) {
            s[kg] = mfma_bf16(aq0, kb[cur][kg][0], s[kg]);
            s[kg] = mfma_bf16(aq1, kb[cur][kg][1], s[kg]);
        }

        if (kt < Sq / 64 - 1) {   // prefetch next K tile while softmax chain runs
            #pragma unroll
            for (int kg = 0; kg < 4; ++kg) {
                kb[nxt][kg][0] = *(const bf16x8*)(kbase + (size_t)(k0 + 64 + kg * 16) * Hq);
                kb[nxt][kg][1] = *(const bf16x8*)(kbase + (size_t)(k0 + 64 + kg * 16) * Hq + 32);
            }
        }

        // V fragments for this tile — issue loads before the exp/LDS chain
        bf16x8 vb[4][2];
        #pragma unroll
        for (int j = 0; j < 4; ++j) {
            vb[j][0] = *(const bf16x8*)(vbase + (size_t)(j * 16) * Sq + k0);
            vb[j][1] = *(const bf16x8*)(vbase + (size_t)(j * 16) * Sq + k0 + 32);
        }

        float p[4][4];
        #pragma unroll
        for (int kg = 0; kg < 4; ++kg) {
            const float mk = amask[b * Sq + k0 + kg * 16 + l16];
            #pragma unroll
            for (int r = 0; r < 4; ++r) {
                p[kg][r] = __expf(s[kg][r] * scale + mk);
                ts[r] += p[kg][r];
            }
        }

        // C-layout -> LDS -> A-layout (same-wave DS ops are in-order; no barrier)
        #pragma unroll
        for (int kg = 0; kg < 4; ++kg)
            #pragma unroll
            for (int r = 0; r < 4; ++r)
                Plds[(quad * 4 + r) * 72 + kg * 16 + l16] = f2bf(p[kg][r]);
        const bf16x8 pa0 = *(const bf16x8*)&Plds[l16 * 72 + quad * 8];
        const bf16x8 pa1 = *(const bf16x8*)&Plds[l16 * 72 + 32 + quad * 8];

        #pragma unroll
        for (int j = 0; j < 4; ++j) {
            O[j] = mfma_bf16(pa0, vb[j][0], O[j]);
            O[j] = mfma_bf16(pa1, vb[j][1], O[j]);
        }
    }

    #pragma unroll
    for (int off = 1; off < 16; off <<= 1)
        #pragma unroll
        for (int r = 0; r < 4; ++r) ts[r] += __shfl_xor(ts[r], off);

    #pragma unroll
    for (int r = 0; r < 4; ++r) {
        const float inv = 1.f / ts[r];
        const int row = q0 + quad * 4 + r;
        #pragma unroll
        for (int j = 0; j < 4; ++j) {
            const int col = h * HDq + j * 16 + l16;
            outp[((size_t)(b * Sq + row)) * Hq + col] += O[j][r] * inv;
        }
    }
}

extern "C" void kernel_launch(void* const* d_in, const int* in_sizes, int n_in,
                              void* d_out, int out_size, void* d_ws, size_t ws_size,
                              hipStream_t stream) {
    (void)in_sizes; (void)n_in; (void)out_size; (void)ws_size;
    const float* from_h = (const float*)d_in[0];
    const float* to_h   = (const float*)d_in[1];
    const float* amask  = (const float*)d_in[2];
    const float* Wq  = (const float*)d_in[3];
    const float* bqv = (const float*)d_in[4];
    const float* Wk  = (const float*)d_in[5];
    const float* bkv = (const float*)d_in[6];
    const float* Wvf = (const float*)d_in[7];
    const float* bvf = (const float*)d_in[8];
    const float* Wvt = (const float*)d_in[9];
    const float* bvt = (const float*)d_in[10];
    float* outp = (float*)d_out;

    unsigned short* ws = (unsigned short*)d_ws;
    unsigned short* qbf = ws;
    unsigned short* kbf = ws + SHsz;
    unsigned short* vtt = ws + 2 * SHsz;
    unsigned short* fbf = ws + 3 * SHsz;
    unsigned short* tbf = ws + 4 * SHsz;
    unsigned short* wqb  = ws + 5 * SHsz;
    unsigned short* wkb  = wqb + WSZ;
    unsigned short* wvfb = wqb + 2 * WSZ;
    unsigned short* wvtb = wqb + 3 * WSZ;

    cvt_kernel<<<dim3(384, 6), 256, 0, stream>>>(from_h, to_h, Wq, Wk, Wvf, Wvt, ws);

    dim3 gp(12, 8, 4);
    proj_gemm<<<gp, 256, 0, stream>>>(fbf, tbf, wqb, wkb, wvfb, wvtb,
                                      bqv, bkv, bvf, bvt, qbf, kbf, vtt, outp);

    dim3 ga(Sq / 16, NHq, Bq);
    attn_kernel<<<ga, 64, 0, stream>>>(qbf, kbf, vtt, amask, outp);
}

// Round 4
// 108.091 us; speedup vs baseline: 1.0688x; 1.0688x over previous
//
#include <hip/hip_runtime.h>
#include <hip/hip_bf16.h>
#include <math.h>

#define Bq  2
#define Sq  512
#define Hq  768
#define NHq 12
#define HDq 64
#define SHsz (Bq * Sq * Hq)   // 786432 elems
#define WSZ  (Hq * Hq)        // 589824 elems

typedef __bf16 bf16x8 __attribute__((ext_vector_type(8)));
typedef unsigned short u16x8 __attribute__((ext_vector_type(8)));
typedef float f32x4 __attribute__((ext_vector_type(4)));

static __device__ __forceinline__ unsigned short f2bf(float f) {
    unsigned int u = __float_as_uint(f);
    u += 0x7fffu + ((u >> 16) & 1u);
    return (unsigned short)(u >> 16);
}

static __device__ __forceinline__ f32x4 mfma_bf16(bf16x8 a, bf16x8 b, f32x4 c) {
    return __builtin_amdgcn_mfma_f32_16x16x32_bf16(a, b, c, 0, 0, 0);
}

static __device__ __forceinline__ void async16(const void* g, void* l) {
    __builtin_amdgcn_global_load_lds(
        (const __attribute__((address_space(1))) void*)(uintptr_t)g,
        (__attribute__((address_space(3))) void*)(unsigned int)(uintptr_t)l,
        16, 0, 0);
}

// ---------------- fp32 -> bf16 pre-convert (inputs + 4 weights) ----------------
__global__ __launch_bounds__(256) void cvt_kernel(
    const float* __restrict__ from_h, const float* __restrict__ to_h,
    const float* __restrict__ Wq, const float* __restrict__ Wk,
    const float* __restrict__ Wvf, const float* __restrict__ Wvt,
    unsigned short* __restrict__ ws)
{
    const int z = blockIdx.y;
    const float* src; unsigned short* dst; int n;
    switch (z) {
        case 0:  src = from_h; dst = ws + 3 * SHsz;           n = SHsz; break;
        case 1:  src = to_h;   dst = ws + 4 * SHsz;           n = SHsz; break;
        case 2:  src = Wq;     dst = ws + 5 * SHsz;           n = WSZ;  break;
        case 3:  src = Wk;     dst = ws + 5 * SHsz + WSZ;     n = WSZ;  break;
        case 4:  src = Wvf;    dst = ws + 5 * SHsz + 2 * WSZ; n = WSZ;  break;
        default: src = Wvt;    dst = ws + 5 * SHsz + 3 * WSZ; n = WSZ;  break;
    }
    const int idx = (blockIdx.x * 256 + threadIdx.x) * 8;
    if (idx < n) {
        const float4 a = *(const float4*)(src + idx);
        const float4 b = *(const float4*)(src + idx + 4);
        u16x8 o = { f2bf(a.x), f2bf(a.y), f2bf(a.z), f2bf(a.w),
                    f2bf(b.x), f2bf(b.y), f2bf(b.z), f2bf(b.w) };
        *(u16x8*)(dst + idx) = o;
    }
}

// ---------------- projections (R2 config): C = A @ W^T + b, 64x64 tile, BK=64 ----------------
__global__ __launch_bounds__(256) void proj_gemm(
    const unsigned short* __restrict__ fbf, const unsigned short* __restrict__ tbf,
    const unsigned short* __restrict__ wqb, const unsigned short* __restrict__ wkb,
    const unsigned short* __restrict__ wvfb, const unsigned short* __restrict__ wvtb,
    const float* __restrict__ bq, const float* __restrict__ bk,
    const float* __restrict__ bvf, const float* __restrict__ bvt,
    unsigned short* __restrict__ qbf, unsigned short* __restrict__ kbf,
    unsigned short* __restrict__ vtt, float* __restrict__ outp)
{
    __shared__ unsigned short lds[8192];
    unsigned short* Als = lds;
    unsigned short* Wls = lds + 4096;

    const int z = blockIdx.z;
    const unsigned short *A, *W;
    const float* bias;
    if (z == 0)      { A = fbf; W = wqb;  bias = bq;  }
    else if (z == 1) { A = tbf; W = wkb;  bias = bk;  }
    else if (z == 2) { A = tbf; W = wvtb; bias = bvt; }
    else             { A = fbf; W = wvfb; bias = bvf; }

    const int t    = threadIdx.x;
    const int wv   = t >> 6;
    const int lane = t & 63;
    const int l16  = lane & 15;
    const int quad = lane >> 4;
    const int bn = blockIdx.x;   // 0..11
    const int bm = blockIdx.y;   // 0..15

    const int srow = lane >> 3;
    const int sgrp = (lane & 7) ^ (srow & 7);

    f32x4 acc[4] = {};

    for (int kt = 0; kt < Hq / 64; ++kt) {
        __syncthreads();
        #pragma unroll
        for (int c = 0; c < 2; ++c) {
            const int r0 = wv * 16 + c * 8;
            async16(A + (size_t)(bm * 64 + r0 + srow) * Hq + kt * 64 + sgrp * 8, &Als[r0 * 64]);
            async16(W + (size_t)(bn * 64 + r0 + srow) * Hq + kt * 64 + sgrp * 8, &Wls[r0 * 64]);
        }
        __syncthreads();

        #pragma unroll
        for (int kk = 0; kk < 2; ++kk) {
            const int sg = ((kk * 4 + quad) ^ (l16 & 7)) * 8;
            const bf16x8 af = *(const bf16x8*)&Als[(wv * 16 + l16) * 64 + sg];
            #pragma unroll
            for (int j = 0; j < 4; ++j) {
                const bf16x8 bfr = *(const bf16x8*)&Wls[(j * 16 + l16) * 64 + sg];
                acc[j] = mfma_bf16(af, bfr, acc[j]);
            }
        }
    }

    __syncthreads();

    if (z == 3) {
        #pragma unroll
        for (int j = 0; j < 4; ++j) {
            const int ncol = bn * 64 + j * 16 + l16;
            const float bv = bias[ncol];
            #pragma unroll
            for (int r = 0; r < 4; ++r) {
                const int m = bm * 64 + wv * 16 + quad * 4 + r;
                outp[(size_t)m * Hq + ncol] = acc[j][r] + bv;
            }
        }
        return;
    }

    unsigned short* rep = lds;
    if (z == 2) {
        #pragma unroll
        for (int j = 0; j < 4; ++j) {
            const float bv = bias[bn * 64 + j * 16 + l16];
            #pragma unroll
            for (int r = 0; r < 4; ++r)
                rep[(j * 16 + l16) * 72 + wv * 16 + quad * 4 + r] = f2bf(acc[j][r] + bv);
        }
    } else {
        #pragma unroll
        for (int j = 0; j < 4; ++j) {
            const float bv = bias[bn * 64 + j * 16 + l16];
            #pragma unroll
            for (int r = 0; r < 4; ++r)
                rep[(wv * 16 + quad * 4 + r) * 72 + j * 16 + l16] = f2bf(acc[j][r] + bv);
        }
    }
    __syncthreads();

    const int row = t >> 2;
    #pragma unroll
    for (int p = 0; p < 2; ++p) {
        const int col0 = ((t & 3) + p * 4) * 8;
        const u16x8 v = *(const u16x8*)&rep[row * 72 + col0];
        if (z == 2) {
            const int bb = bm >> 3, m0 = (bm & 7) * 64;
            *(u16x8*)&vtt[((size_t)((bb * NHq + bn) * HDq + row)) * Sq + m0 + col0] = v;
        } else {
            unsigned short* dstp = (z == 0) ? qbf : kbf;
            *(u16x8*)&dstp[(size_t)(bm * 64 + row) * Hq + bn * 64 + col0] = v;
        }
    }
}

// ---------------- attention, split-K: 2 waves/block each cover 256 k-positions ----------------
// Partials are additive (no running max), combined once via LDS. Grid (32,12,2), 128 thr.
__global__ __launch_bounds__(128) void attn_kernel(
    const unsigned short* __restrict__ qbf,
    const unsigned short* __restrict__ kbf,
    const unsigned short* __restrict__ vtt,
    const float* __restrict__ amask,
    float* __restrict__ outp)
{
    __shared__ unsigned short Plds[2 * 16 * 40];   // per-wave P repack
    __shared__ float Ols[16 * 68];                 // wave1 partial O (stride 68 -> 2-way max)
    __shared__ float Tls[16];                      // wave1 partial denom

    const int t    = threadIdx.x;
    const int wv   = t >> 6;       // 0,1: k-range split
    const int lane = t & 63;
    const int l16  = lane & 15;
    const int quad = lane >> 4;
    const int q0 = blockIdx.x * 16;
    const int h  = blockIdx.y;
    const int b  = blockIdx.z;

    const unsigned short* qrow = qbf + ((size_t)(b * Sq + q0 + l16)) * Hq + h * HDq + quad * 8;
    const bf16x8 aq0 = *(const bf16x8*)qrow;
    const bf16x8 aq1 = *(const bf16x8*)(qrow + 32);

    f32x4 O[4] = {};
    float ts[4] = {0.f, 0.f, 0.f, 0.f};
    const float scale = 0.125f;
    unsigned short* myP = &Plds[wv * 16 * 40];

    for (int kt = 0; kt < 8; ++kt) {
        const int k0 = wv * 256 + kt * 32;
        const unsigned short* kr = kbf + ((size_t)(b * Sq + k0 + l16)) * Hq + h * HDq + quad * 8;
        const bf16x8 kb00 = *(const bf16x8*)kr;
        const bf16x8 kb01 = *(const bf16x8*)(kr + 32);
        const bf16x8 kb10 = *(const bf16x8*)(kr + 16 * Hq);
        const bf16x8 kb11 = *(const bf16x8*)(kr + 16 * Hq + 32);

        f32x4 s0 = {}, s1 = {};
        s0 = mfma_bf16(aq0, kb00, s0);
        s0 = mfma_bf16(aq1, kb01, s0);
        s1 = mfma_bf16(aq0, kb10, s1);
        s1 = mfma_bf16(aq1, kb11, s1);

        const float mk0 = amask[b * Sq + k0 + l16];
        const float mk1 = amask[b * Sq + k0 + 16 + l16];

        float p0[4], p1[4];
        #pragma unroll
        for (int r = 0; r < 4; ++r) {
            p0[r] = __expf(s0[r] * scale + mk0);
            p1[r] = __expf(s1[r] * scale + mk1);
            ts[r] += p0[r] + p1[r];
        }

        #pragma unroll
        for (int r = 0; r < 4; ++r) {
            myP[(quad * 4 + r) * 40 + l16]      = f2bf(p0[r]);
            myP[(quad * 4 + r) * 40 + 16 + l16] = f2bf(p1[r]);
        }
        const bf16x8 pa = *(const bf16x8*)&myP[l16 * 40 + quad * 8];

        const unsigned short* vr = vtt + ((size_t)((b * NHq + h) * HDq + l16)) * Sq + k0 + quad * 8;
        #pragma unroll
        for (int j = 0; j < 4; ++j) {
            const bf16x8 vb = *(const bf16x8*)(vr + (size_t)j * 16 * Sq);
            O[j] = mfma_bf16(pa, vb, O[j]);
        }
    }

    // reduce denom across the 16 l16 lanes (quad preserved: xor < 16)
    #pragma unroll
    for (int off = 1; off < 16; off <<= 1)
        #pragma unroll
        for (int r = 0; r < 4; ++r) ts[r] += __shfl_xor(ts[r], off);

    // wave1 publishes partials; wave0 combines and writes
    if (wv == 1) {
        #pragma unroll
        for (int j = 0; j < 4; ++j)
            #pragma unroll
            for (int r = 0; r < 4; ++r)
                Ols[(quad * 4 + r) * 68 + j * 16 + l16] = O[j][r];
        if (l16 == 0)
            #pragma unroll
            for (int r = 0; r < 4; ++r) Tls[quad * 4 + r] = ts[r];
    }
    __syncthreads();
    if (wv == 1) return;

    #pragma unroll
    for (int r = 0; r < 4; ++r) {
        const float l = ts[r] + Tls[quad * 4 + r];
        const float inv = 1.f / l;
        const int row = q0 + quad * 4 + r;
        #pragma unroll
        for (int j = 0; j < 4; ++j) {
            const int col = h * HDq + j * 16 + l16;
            const float oj = O[j][r] + Ols[(quad * 4 + r) * 68 + j * 16 + l16];
            outp[((size_t)(b * Sq + row)) * Hq + col] += oj * inv;
        }
    }
}

extern "C" void kernel_launch(void* const* d_in, const int* in_sizes, int n_in,
                              void* d_out, int out_size, void* d_ws, size_t ws_size,
                              hipStream_t stream) {
    (void)in_sizes; (void)n_in; (void)out_size; (void)ws_size;
    const float* from_h = (const float*)d_in[0];
    const float* to_h   = (const float*)d_in[1];
    const float* amask  = (const float*)d_in[2];
    const float* Wq  = (const float*)d_in[3];
    const float* bqv = (const float*)d_in[4];
    const float* Wk  = (const float*)d_in[5];
    const float* bkv = (const float*)d_in[6];
    const float* Wvf = (const float*)d_in[7];
    const float* bvf = (const float*)d_in[8];
    const float* Wvt = (const float*)d_in[9];
    const float* bvt = (const float*)d_in[10];
    float* outp = (float*)d_out;

    unsigned short* ws = (unsigned short*)d_ws;
    unsigned short* qbf = ws;
    unsigned short* kbf = ws + SHsz;
    unsigned short* vtt = ws + 2 * SHsz;
    unsigned short* fbf = ws + 3 * SHsz;
    unsigned short* tbf = ws + 4 * SHsz;
    unsigned short* wqb  = ws + 5 * SHsz;
    unsigned short* wkb  = wqb + WSZ;
    unsigned short* wvfb = wqb + 2 * WSZ;
    unsigned short* wvtb = wqb + 3 * WSZ;

    cvt_kernel<<<dim3(384, 6), 256, 0, stream>>>(from_h, to_h, Wq, Wk, Wvf, Wvt, ws);

    dim3 gp(12, 16, 4);
    proj_gemm<<<gp, 256, 0, stream>>>(fbf, tbf, wqb, wkb, wvfb, wvtb,
                                      bqv, bkv, bvf, bvt, qbf, kbf, vtt, outp);

    dim3 ga(Sq / 16, NHq, Bq);
    attn_kernel<<<ga, 128, 0, stream>>>(qbf, kbf, vtt, amask, outp);
}

// Round 5
// 107.421 us; speedup vs baseline: 1.0755x; 1.0062x over previous
//
#include <hip/hip_runtime.h>
#include <hip/hip_bf16.h>
#include <math.h>

#define Bq  2
#define Sq  512
#define Hq  768
#define NHq 12
#define HDq 64
#define SHsz (Bq * Sq * Hq)   // 786432 elems
#define WSZ  (Hq * Hq)        // 589824 elems

typedef __bf16 bf16x8 __attribute__((ext_vector_type(8)));
typedef unsigned short u16x8 __attribute__((ext_vector_type(8)));
typedef float f32x4 __attribute__((ext_vector_type(4)));

static __device__ __forceinline__ unsigned short f2bf(float f) {
    unsigned int u = __float_as_uint(f);
    u += 0x7fffu + ((u >> 16) & 1u);
    return (unsigned short)(u >> 16);
}
static __device__ __forceinline__ float bf2f(unsigned short v) {
    return __uint_as_float(((unsigned int)v) << 16);
}

static __device__ __forceinline__ f32x4 mfma_bf16(bf16x8 a, bf16x8 b, f32x4 c) {
    return __builtin_amdgcn_mfma_f32_16x16x32_bf16(a, b, c, 0, 0, 0);
}

static __device__ __forceinline__ void async16(const void* g, void* l) {
    __builtin_amdgcn_global_load_lds(
        (const __attribute__((address_space(1))) void*)(uintptr_t)g,
        (__attribute__((address_space(3))) void*)(unsigned int)(uintptr_t)l,
        16, 0, 0);
}

// ---------------- fp32 -> bf16 pre-convert (inputs + 4 weights) ----------------
__global__ __launch_bounds__(256) void cvt_kernel(
    const float* __restrict__ from_h, const float* __restrict__ to_h,
    const float* __restrict__ Wq, const float* __restrict__ Wk,
    const float* __restrict__ Wvf, const float* __restrict__ Wvt,
    unsigned short* __restrict__ ws)
{
    const int z = blockIdx.y;
    const float* src; unsigned short* dst; int n;
    switch (z) {
        case 0:  src = from_h; dst = ws + 3 * SHsz;           n = SHsz; break;
        case 1:  src = to_h;   dst = ws + 4 * SHsz;           n = SHsz; break;
        case 2:  src = Wq;     dst = ws + 5 * SHsz;           n = WSZ;  break;
        case 3:  src = Wk;     dst = ws + 5 * SHsz + WSZ;     n = WSZ;  break;
        case 4:  src = Wvf;    dst = ws + 5 * SHsz + 2 * WSZ; n = WSZ;  break;
        default: src = Wvt;    dst = ws + 5 * SHsz + 3 * WSZ; n = WSZ;  break;
    }
    const int idx = (blockIdx.x * 256 + threadIdx.x) * 8;
    if (idx < n) {
        const float4 a = *(const float4*)(src + idx);
        const float4 b = *(const float4*)(src + idx + 4);
        u16x8 o = { f2bf(a.x), f2bf(a.y), f2bf(a.z), f2bf(a.w),
                    f2bf(b.x), f2bf(b.y), f2bf(b.z), f2bf(b.w) };
        *(u16x8*)(dst + idx) = o;
    }
}

// ---------------- projections: C = A @ W^T + b, 64x64 tile, BK=128 (two 64-wide halves) ----------------
// z=0: Q -> qbf [B*S,H]; z=1: K -> kbf; z=2: VT -> vtt [(b*NH+h)*HD+d, S]; z=3: VF -> vfb bf16 [B*S,H]
__global__ __launch_bounds__(256) void proj_gemm(
    const unsigned short* __restrict__ fbf, const unsigned short* __restrict__ tbf,
    const unsigned short* __restrict__ wqb, const unsigned short* __restrict__ wkb,
    const unsigned short* __restrict__ wvfb, const unsigned short* __restrict__ wvtb,
    const float* __restrict__ bq, const float* __restrict__ bk,
    const float* __restrict__ bvf, const float* __restrict__ bvt,
    unsigned short* __restrict__ qbf, unsigned short* __restrict__ kbf,
    unsigned short* __restrict__ vtt, unsigned short* __restrict__ vfb)
{
    __shared__ unsigned short lds[16384];  // A halves [0,8192), W halves [8192,16384)
    unsigned short* Als = lds;
    unsigned short* Wls = lds + 8192;

    const int z = blockIdx.z;
    const unsigned short *A, *W;
    const float* bias;
    if (z == 0)      { A = fbf; W = wqb;  bias = bq;  }
    else if (z == 1) { A = tbf; W = wkb;  bias = bk;  }
    else if (z == 2) { A = tbf; W = wvtb; bias = bvt; }
    else             { A = fbf; W = wvfb; bias = bvf; }

    const int t    = threadIdx.x;
    const int wv   = t >> 6;
    const int lane = t & 63;
    const int l16  = lane & 15;
    const int quad = lane >> 4;
    const int bn = blockIdx.x;   // 0..11
    const int bm = blockIdx.y;   // 0..15

    const int srow = lane >> 3;                 // 0..7
    const int sgrp = (lane & 7) ^ (srow & 7);   // logical k-group for the swizzled store slot

    f32x4 acc[4] = {};

    for (int kt = 0; kt < Hq / 128; ++kt) {
        __syncthreads();
        #pragma unroll
        for (int kh = 0; kh < 2; ++kh) {
            const int kc = kt * 128 + kh * 64;
            #pragma unroll
            for (int c = 0; c < 2; ++c) {
                const int r0 = wv * 16 + c * 8;
                async16(A + (size_t)(bm * 64 + r0 + srow) * Hq + kc + sgrp * 8, &Als[kh * 4096 + r0 * 64]);
                async16(W + (size_t)(bn * 64 + r0 + srow) * Hq + kc + sgrp * 8, &Wls[kh * 4096 + r0 * 64]);
            }
        }
        __syncthreads();

        #pragma unroll
        for (int kh = 0; kh < 2; ++kh) {
            #pragma unroll
            for (int kk = 0; kk < 2; ++kk) {
                const int sg = kh * 4096 + ((kk * 4 + quad) ^ (l16 & 7)) * 8;
                const bf16x8 af = *(const bf16x8*)&Als[(wv * 16 + l16) * 64 + sg];
                #pragma unroll
                for (int j = 0; j < 4; ++j) {
                    const bf16x8 bfr = *(const bf16x8*)&Wls[(j * 16 + l16) * 64 + sg];
                    acc[j] = mfma_bf16(af, bfr, acc[j]);
                }
            }
        }
    }

    __syncthreads();   // LDS free for repack

    unsigned short* rep = lds;   // stride 72 shorts (144 B, 16B-aligned)
    if (z == 2) {
        // transposed repack: rep[n_local][m_local]
        #pragma unroll
        for (int j = 0; j < 4; ++j) {
            const float bv = bias[bn * 64 + j * 16 + l16];
            #pragma unroll
            for (int r = 0; r < 4; ++r)
                rep[(j * 16 + l16) * 72 + wv * 16 + quad * 4 + r] = f2bf(acc[j][r] + bv);
        }
    } else {
        #pragma unroll
        for (int j = 0; j < 4; ++j) {
            const float bv = bias[bn * 64 + j * 16 + l16];
            #pragma unroll
            for (int r = 0; r < 4; ++r)
                rep[(wv * 16 + quad * 4 + r) * 72 + j * 16 + l16] = f2bf(acc[j][r] + bv);
        }
    }
    __syncthreads();

    const int row = t >> 2;
    #pragma unroll
    for (int p = 0; p < 2; ++p) {
        const int col0 = ((t & 3) + p * 4) * 8;
        const u16x8 v = *(const u16x8*)&rep[row * 72 + col0];
        if (z == 2) {
            const int bb = bm >> 3, m0 = (bm & 7) * 64;
            *(u16x8*)&vtt[((size_t)((bb * NHq + bn) * HDq + row)) * Sq + m0 + col0] = v;
        } else {
            unsigned short* dstp = (z == 0) ? qbf : (z == 1) ? kbf : vfb;
            *(u16x8*)&dstp[(size_t)(bm * 64 + row) * Hq + bn * 64 + col0] = v;
        }
    }
}

// ---------------- attention, split-K: 2 waves/block each cover 256 k-positions ----------------
// out = softmax(QK^T/8 + mask) @ VT + VF. Partials additive (no running max), combined via LDS.
__global__ __launch_bounds__(128) void attn_kernel(
    const unsigned short* __restrict__ qbf,
    const unsigned short* __restrict__ kbf,
    const unsigned short* __restrict__ vtt,
    const unsigned short* __restrict__ vfb,
    const float* __restrict__ amask,
    float* __restrict__ outp)
{
    __shared__ unsigned short Plds[2 * 16 * 40];   // per-wave P repack
    __shared__ float Ols[16 * 68];                 // wave1 partial O (2-way max)
    __shared__ float Tls[16];                      // wave1 partial denom

    const int t    = threadIdx.x;
    const int wv   = t >> 6;       // k-range split
    const int lane = t & 63;
    const int l16  = lane & 15;
    const int quad = lane >> 4;
    const int q0 = blockIdx.x * 16;
    const int h  = blockIdx.y;
    const int b  = blockIdx.z;

    const unsigned short* qrow = qbf + ((size_t)(b * Sq + q0 + l16)) * Hq + h * HDq + quad * 8;
    const bf16x8 aq0 = *(const bf16x8*)qrow;
    const bf16x8 aq1 = *(const bf16x8*)(qrow + 32);

    f32x4 O[4] = {};
    float ts[4] = {0.f, 0.f, 0.f, 0.f};
    const float scale = 0.125f;
    unsigned short* myP = &Plds[wv * 16 * 40];

    for (int kt = 0; kt < 8; ++kt) {
        const int k0 = wv * 256 + kt * 32;
        const unsigned short* kr = kbf + ((size_t)(b * Sq + k0 + l16)) * Hq + h * HDq + quad * 8;
        const bf16x8 kb00 = *(const bf16x8*)kr;
        const bf16x8 kb01 = *(const bf16x8*)(kr + 32);
        const bf16x8 kb10 = *(const bf16x8*)(kr + 16 * Hq);
        const bf16x8 kb11 = *(const bf16x8*)(kr + 16 * Hq + 32);

        f32x4 s0 = {}, s1 = {};
        s0 = mfma_bf16(aq0, kb00, s0);
        s0 = mfma_bf16(aq1, kb01, s0);
        s1 = mfma_bf16(aq0, kb10, s1);
        s1 = mfma_bf16(aq1, kb11, s1);

        const float mk0 = amask[b * Sq + k0 + l16];
        const float mk1 = amask[b * Sq + k0 + 16 + l16];

        float p0[4], p1[4];
        #pragma unroll
        for (int r = 0; r < 4; ++r) {
            p0[r] = __expf(s0[r] * scale + mk0);
            p1[r] = __expf(s1[r] * scale + mk1);
            ts[r] += p0[r] + p1[r];
        }

        #pragma unroll
        for (int r = 0; r < 4; ++r) {
            myP[(quad * 4 + r) * 40 + l16]      = f2bf(p0[r]);
            myP[(quad * 4 + r) * 40 + 16 + l16] = f2bf(p1[r]);
        }
        const bf16x8 pa = *(const bf16x8*)&myP[l16 * 40 + quad * 8];

        const unsigned short* vr = vtt + ((size_t)((b * NHq + h) * HDq + l16)) * Sq + k0 + quad * 8;
        #pragma unroll
        for (int j = 0; j < 4; ++j) {
            const bf16x8 vb = *(const bf16x8*)(vr + (size_t)j * 16 * Sq);
            O[j] = mfma_bf16(pa, vb, O[j]);
        }
    }

    #pragma unroll
    for (int off = 1; off < 16; off <<= 1)
        #pragma unroll
        for (int r = 0; r < 4; ++r) ts[r] += __shfl_xor(ts[r], off);

    if (wv == 1) {
        #pragma unroll
        for (int j = 0; j < 4; ++j)
            #pragma unroll
            for (int r = 0; r < 4; ++r)
                Ols[(quad * 4 + r) * 68 + j * 16 + l16] = O[j][r];
        if (l16 == 0)
            #pragma unroll
            for (int r = 0; r < 4; ++r) Tls[quad * 4 + r] = ts[r];
    }
    __syncthreads();
    if (wv == 1) return;

    #pragma unroll
    for (int r = 0; r < 4; ++r) {
        const float inv = 1.f / (ts[r] + Tls[quad * 4 + r]);
        const int row = q0 + quad * 4 + r;
        #pragma unroll
        for (int j = 0; j < 4; ++j) {
            const int col = h * HDq + j * 16 + l16;
            const size_t idx = ((size_t)(b * Sq + row)) * Hq + col;
            const float oj = O[j][r] + Ols[(quad * 4 + r) * 68 + j * 16 + l16];
            outp[idx] = oj * inv + bf2f(vfb[idx]);
        }
    }
}

extern "C" void kernel_launch(void* const* d_in, const int* in_sizes, int n_in,
                              void* d_out, int out_size, void* d_ws, size_t ws_size,
                              hipStream_t stream) {
    (void)in_sizes; (void)n_in; (void)out_size; (void)ws_size;
    const float* from_h = (const float*)d_in[0];
    const float* to_h   = (const float*)d_in[1];
    const float* amask  = (const float*)d_in[2];
    const float* Wq  = (const float*)d_in[3];
    const float* bqv = (const float*)d_in[4];
    const float* Wk  = (const float*)d_in[5];
    const float* bkv = (const float*)d_in[6];
    const float* Wvf = (const float*)d_in[7];
    const float* bvf = (const float*)d_in[8];
    const float* Wvt = (const float*)d_in[9];
    const float* bvt = (const float*)d_in[10];
    float* outp = (float*)d_out;

    unsigned short* ws = (unsigned short*)d_ws;
    unsigned short* qbf = ws;
    unsigned short* kbf = ws + SHsz;
    unsigned short* vtt = ws + 2 * SHsz;
    unsigned short* fbf = ws + 3 * SHsz;
    unsigned short* tbf = ws + 4 * SHsz;
    unsigned short* wqb  = ws + 5 * SHsz;
    unsigned short* wkb  = wqb + WSZ;
    unsigned short* wvfb = wqb + 2 * WSZ;
    unsigned short* wvtb = wqb + 3 * WSZ;
    unsigned short* vfb  = wqb + 4 * WSZ;

    cvt_kernel<<<dim3(384, 6), 256, 0, stream>>>(from_h, to_h, Wq, Wk, Wvf, Wvt, ws);

    dim3 gp(12, 16, 4);
    proj_gemm<<<gp, 256, 0, stream>>>(fbf, tbf, wqb, wkb, wvfb, wvtb,
                                      bqv, bkv, bvf, bvt, qbf, kbf, vtt, vfb);

    dim3 ga(Sq / 16, NHq, Bq);
    attn_kernel<<<ga, 128, 0, stream>>>(qbf, kbf, vtt, vfb, amask, outp);
}